// Round 8
// baseline (202.915 us; speedup 1.0000x reference)
//
#include <hip/hip_runtime.h>
#include <math.h>

#define Bn 4
#define Cn 64
#define Ln 4096
#define CQ 16
#define NH 4
#define NB 32
#define EPSV 1e-5f

#define MAXS 384    // max bucket size (mean 128, sigma ~11)
#define SFULL 192   // full-bucket LDS staging limit (mean+5.8sigma)

#define QSZ   (Bn*Ln*CQ)      // 262144 floats
#define VSZ   (Bn*Ln*Cn)      // 1048576 floats
#define ACCSZ (Bn*Ln*Cn)
#define NBH   (Bn*NH)         // 16

// layout (float units): [q][k][v][acc x4|x1][Psum 16384][Psq 16384][cnt]
#define OFF_K   QSZ
#define OFF_V   (2*QSZ)
#define OFF_ACC (2*QSZ + VSZ)

#define LOG2E 1.44269504088896f
#define WSTR 36     // proj sWt stride: 36c+8og stays 16B-aligned, banks spread
#define OSTR 68     // fused sWt/sA stride: 68c+8og 16B-aligned
#define NBLK_F 256  // fused grid: 256 blocks == #CUs -> co-residency guaranteed
#define FPOS 64     // positions per fused block

// 768 blocks: (pos-group of 64) x (row-third of 32); og owns 8 rows
// block 0 zero-inits the fused kernel's barrier counter (2 kernels upstream)
__global__ __launch_bounds__(256) void proj_kernel(
        const float* __restrict__ x,
        const float* __restrict__ Wq, const float* __restrict__ bq,
        const float* __restrict__ Wk, const float* __restrict__ bk,
        const float* __restrict__ Wv, const float* __restrict__ bv,
        float* __restrict__ q, float* __restrict__ k, float* __restrict__ v,
        int* __restrict__ cnt) {
    __shared__ float sWt[Cn*WSTR];   // [c][rr] stride 36
    __shared__ float sb[32];
    int tid = threadIdx.x;
    if (blockIdx.x == 0 && tid == 0) *cnt = 0;
    int third = blockIdx.x % 3;
    int pg    = blockIdx.x / 3;
    int rbase = third * 32;
    // coalesced weight load: consecutive lanes <- consecutive c of one W row
    for (int idx = tid; idx < 32*Cn; idx += 256) {
        int c = idx & 63, rr = idx >> 6;
        int r = rbase + rr;
        float w;
        if (r < 16)      w = Wq[r*Cn + c];
        else if (r < 32) w = Wk[(r-16)*Cn + c];
        else             w = Wv[(r-32)*Cn + c];
        sWt[c*WSTR + rr] = w;        // 8-way write conflict (2.9x), 8 iters only
    }
    if (tid < 32) {
        int r = rbase + tid;
        sb[tid] = (r < 16) ? bq[r] : (r < 32 ? bk[r-16] : bv[r-32]);
    }
    __syncthreads();
    int p = tid & 63, og = tid >> 6;       // og uniform per wave
    int gp = pg * 64 + p;                  // flattened position b*L + l
    int b = gp >> 12, l = gp & (Ln - 1);
    const float* xp = &x[b*Cn*Ln + l];
    int rr0 = og * 8;
    float val[8];
    #pragma unroll
    for (int i = 0; i < 8; i++) val[i] = sb[rr0 + i];
    #pragma unroll
    for (int c0 = 0; c0 < Cn; c0 += 8) {
        float xv[8];
        #pragma unroll
        for (int i = 0; i < 8; i++) xv[i] = xp[(c0 + i)*Ln];   // coalesced in p
        #pragma unroll
        for (int i = 0; i < 8; i++) {
            const float4 wa = *(const float4*)&sWt[(c0 + i)*WSTR + rr0];
            const float4 wb = *(const float4*)&sWt[(c0 + i)*WSTR + rr0 + 4];
            float xvi = xv[i];
            val[0] = fmaf(wa.x, xvi, val[0]); val[1] = fmaf(wa.y, xvi, val[1]);
            val[2] = fmaf(wa.z, xvi, val[2]); val[3] = fmaf(wa.w, xvi, val[3]);
            val[4] = fmaf(wb.x, xvi, val[4]); val[5] = fmaf(wb.y, xvi, val[5]);
            val[6] = fmaf(wb.z, xvi, val[6]); val[7] = fmaf(wb.w, xvi, val[7]);
        }
    }
    int f = third*8 + og*2;                // wave-uniform; never straddles q/k/v
    float4 t0 = make_float4(val[0], val[1], val[2], val[3]);
    float4 t1 = make_float4(val[4], val[5], val[6], val[7]);
    float4* q4 = (float4*)&q[gp*CQ];
    float4* k4 = (float4*)&k[gp*CQ];
    float4* v4 = (float4*)&v[gp*Cn];
    if (f < 4)      { q4[f]   = t0; q4[f+1] = t1; }
    else if (f < 8) { k4[f-4] = t0; k4[f-3] = t1; }
    else            { v4[f-8] = t0; v4[f-7] = t1; }
}

// quad (4-lane) butterfly sum via DPP quad_perm — VALU pipe, no LDS
__device__ __forceinline__ float quad_reduce_sum(float d) {
    d += __int_as_float(__builtin_amdgcn_mov_dpp(__float_as_int(d), 0xB1, 0xF, 0xF, true));
    d += __int_as_float(__builtin_amdgcn_mov_dpp(__float_as_int(d), 0x4E, 0xF, 0xF, true));
    return d;
}

// sum over the 4 lanes {r, r-4, r-8, r-12} within a row of 16 (same c4 class);
// result valid at row-tail lanes 12..15. row_shr:4 = 0x114, row_shr:8 = 0x118.
__device__ __forceinline__ float rowsum16(float x) {
    x += __int_as_float(__builtin_amdgcn_mov_dpp(__float_as_int(x), 0x114, 0xF, 0xF, true));
    x += __int_as_float(__builtin_amdgcn_mov_dpp(__float_as_int(x), 0x118, 0xF, 0xF, true));
    return x;
}

// wave covers 4*NS queries per sweep: lane = (qq=l>>4, kk=(l>>2)&3, c4=l&3),
// slot s covers queries q0+s*4 .. +3 via the 4 qq-groups.
// o[s][t] = chs ((qq+t)&3)*16 + c4*4 .. +3.  ir[s]<0 marks inactive slot.
template<int NS> struct Sweep {
    float4 qr[NS];     // lane's c4-quarter of each query, prescaled by log2e
    float4 o[NS][4];
    float  lsum[NS];
    int    ir[NS];
};

template<int NS>
__device__ __forceinline__ void sweep_init(Sweep<NS>& st, int q0, int S, int act,
        const int* list, const float4* Q4, int qq, int c4) {
    #pragma unroll
    for (int s = 0; s < NS; s++) {
        int qi = q0 + s*4 + qq;
        int a = act && (qi < S);
        st.ir[s] = a ? list[qi] : -1;
        float4 t = make_float4(0.f, 0.f, 0.f, 0.f);
        if (a) {
            t = Q4[(size_t)st.ir[s]*4 + c4];
            t.x *= LOG2E; t.y *= LOG2E; t.z *= LOG2E; t.w *= LOG2E;
        }
        st.qr[s] = t;
        st.lsum[s] = 0.f;
        #pragma unroll
        for (int tt = 0; tt < 4; tt++) st.o[s][tt] = make_float4(0.f, 0.f, 0.f, 0.f);
    }
}

// one 4-key block: 1 K b128 + 4 V b128, all conflict-free (R5-proven form)
template<int NS, bool MASKED>
__device__ __forceinline__ void kb_step(Sweep<NS>& st, int kb, int nkv,
        const float4* ks4, const float4* vs4, int l15, int kk,
        int i0, int i1, int i2, int i3) {
    const float4 kq = ks4[kb*16 + l15];
    const float4 va = vs4[kb*64 + i0*16 + l15];
    const float4 vb = vs4[kb*64 + i1*16 + l15];
    const float4 vc = vs4[kb*64 + i2*16 + l15];
    const float4 vd = vs4[kb*64 + i3*16 + l15];
    #pragma unroll
    for (int s = 0; s < NS; s++) {
        float d = st.qr[s].x * kq.x;
        d = fmaf(st.qr[s].y, kq.y, d);
        d = fmaf(st.qr[s].z, kq.z, d);
        d = fmaf(st.qr[s].w, kq.w, d);
        d = quad_reduce_sum(d);                 // full 16-ch dot in all 4 quad lanes
        float pw = __builtin_amdgcn_exp2f(d);
        if (MASKED) pw = ((kb*4 + kk) < nkv) ? pw : 0.f;
        st.lsum[s] += pw;
        st.o[s][0].x = fmaf(pw, va.x, st.o[s][0].x); st.o[s][0].y = fmaf(pw, va.y, st.o[s][0].y);
        st.o[s][0].z = fmaf(pw, va.z, st.o[s][0].z); st.o[s][0].w = fmaf(pw, va.w, st.o[s][0].w);
        st.o[s][1].x = fmaf(pw, vb.x, st.o[s][1].x); st.o[s][1].y = fmaf(pw, vb.y, st.o[s][1].y);
        st.o[s][1].z = fmaf(pw, vb.z, st.o[s][1].z); st.o[s][1].w = fmaf(pw, vb.w, st.o[s][1].w);
        st.o[s][2].x = fmaf(pw, vc.x, st.o[s][2].x); st.o[s][2].y = fmaf(pw, vc.y, st.o[s][2].y);
        st.o[s][2].z = fmaf(pw, vc.z, st.o[s][2].z); st.o[s][2].w = fmaf(pw, vc.w, st.o[s][2].w);
        st.o[s][3].x = fmaf(pw, vd.x, st.o[s][3].x); st.o[s][3].y = fmaf(pw, vd.y, st.o[s][3].y);
        st.o[s][3].z = fmaf(pw, vd.z, st.o[s][3].z); st.o[s][3].w = fmaf(pw, vd.w, st.o[s][3].w);
    }
}

template<int NS>
__device__ __forceinline__ void sweep_keys(Sweep<NS>& st, int nk,
        const float4* ks4, const float4* vs4, int l15, int kk,
        int i0, int i1, int i2, int i3) {
    int nf = nk >> 2;
    for (int kb = 0; kb < nf; kb++)
        kb_step<NS,false>(st, kb, nk, ks4, vs4, l15, kk, i0, i1, i2, i3);
    if (nk & 3)
        kb_step<NS,true>(st, nf, nk, ks4, vs4, l15, kk, i0, i1, i2, i3);
}

// reduce o/lsum over kk (2 DPP row-tail adds, pure VALU); tail lanes 12..15
// of each row (c4 = 0..3) hold the query's full 64 channels; normalize+store
template<int NS, int MODE>
__device__ __forceinline__ void sweep_fin(Sweep<NS>& st, float* __restrict__ acc,
        int b, int h, int qq, int lane, int c4) {
    #pragma unroll
    for (int s = 0; s < NS; s++) {
        st.lsum[s] = rowsum16(st.lsum[s]);
        #pragma unroll
        for (int t = 0; t < 4; t++) {
            st.o[s][t].x = rowsum16(st.o[s][t].x);
            st.o[s][t].y = rowsum16(st.o[s][t].y);
            st.o[s][t].z = rowsum16(st.o[s][t].z);
            st.o[s][t].w = rowsum16(st.o[s][t].w);
        }
    }
    if ((lane & 15) < 12) return;
    #pragma unroll
    for (int s = 0; s < NS; s++) {
        if (st.ir[s] >= 0) {
            float inv = 1.f / st.lsum[s];
            #pragma unroll
            for (int t = 0; t < 4; t++) {
                float4 r;
                r.x = st.o[s][t].x * inv; r.y = st.o[s][t].y * inv;
                r.z = st.o[s][t].z * inv; r.w = st.o[s][t].w * inv;
                int ch = ((qq + t) & 3)*16 + c4*4;
                if (MODE == 1) {
                    *(float4*)&acc[(((size_t)h*Bn + b)*Ln + st.ir[s])*Cn + ch] = r;
                } else {
                    float* ap = &acc[((size_t)b*Ln + st.ir[s])*Cn + ch];
                    atomicAdd(&ap[0], r.x); atomicAdd(&ap[1], r.y);
                    atomicAdd(&ap[2], r.z); atomicAdd(&ap[3], r.w);
                }
            }
        }
    }
}

template<int NS, int MODE>
__device__ __forceinline__ void run_sweep(int q0, int S, int act,
        const int* list, const float4* Q4,
        const float4* ks4, const float4* vs4, float* __restrict__ acc,
        int b, int h, int qq, int lane, int c4, int l15, int kk,
        int i0, int i1, int i2, int i3) {
    Sweep<NS> st;
    sweep_init<NS>(st, q0, S, act, list, Q4, qq, c4);
    sweep_keys<NS>(st, S, ks4, vs4, l15, kk, i0, i1, i2, i3);
    sweep_fin<NS,MODE>(st, acc, b, h, qq, lane, c4);
}

// tiled staging (NT=512): ks4[j*4+c] = K[list[j]] quarter c;
// vs4[(j>>2)*64 + i*16 + (j&3)*4 + c] = V[list[j]][i*16 + c*4 ..+3]
__device__ __forceinline__ void stage_kv(int tid, int nk, int k0, const int* list,
        const float4* K4, const float4* V4, float4* ks4, float4* vs4) {
    const float4 z = make_float4(0.f, 0.f, 0.f, 0.f);
    int nb4 = (nk + 3) >> 2;
    for (int G = tid; G < nb4*16; G += 512) {
        int j = G >> 2;
        ks4[G] = (j < nk) ? K4[(size_t)list[k0 + j]*4 + (G & 3)] : z;
    }
    for (int F = tid; F < nb4*64; F += 512) {
        int kb = F >> 6, ii = (F >> 4) & 3, k2 = (F >> 2) & 3, cc = F & 3;
        int j = kb*4 + k2;
        vs4[F] = (j < nk) ? V4[(size_t)list[k0 + j]*16 + ii*4 + cc] : z;
    }
}

// 512 blocks x 512 threads (8 waves), 2 blocks/CU resident (62KB LDS).
template<int MODE>
__global__ __launch_bounds__(512, 2) void attn_kernel(
        const float* __restrict__ q, const float* __restrict__ k,
        const float* __restrict__ v, const int* __restrict__ hidx,
        float* __restrict__ acc) {
    __shared__ int list[MAXS];
    __shared__ int wtot[8];
    __shared__ float4 ks4[SFULL*4];    // 12 KB
    __shared__ float4 vs4[SFULL*16];   // 48 KB
    int blk = blockIdx.x;              // = bh*NB + u
    int u  = blk & (NB-1);
    int bh = blk >> 5;
    int b  = bh >> 2;
    int h  = bh & 3;
    int tid = threadIdx.x;

    // ---- deterministic ascending bucket list via wave scan (8 ints/thread) ----
    const int4* hp4 = (const int4*)&hidx[bh*Ln + tid*8];
    int hv[8];
    #pragma unroll
    for (int t = 0; t < 2; t++) {
        int4 tmp = hp4[t];
        hv[t*4+0]=tmp.x; hv[t*4+1]=tmp.y; hv[t*4+2]=tmp.z; hv[t*4+3]=tmp.w;
    }
    int myCnt = 0;
    #pragma unroll
    for (int t = 0; t < 8; t++) myCnt += (hv[t] == u);
    int lane = tid & 63, wv = tid >> 6;
    int pre = myCnt;
    #pragma unroll
    for (int d = 1; d < 64; d <<= 1) {
        int t = __shfl_up(pre, d, 64);
        if (lane >= d) pre += t;
    }
    if (lane == 63) wtot[wv] = pre;
    __syncthreads();
    int base = 0, Sall = 0;
    #pragma unroll
    for (int w = 0; w < 8; w++) {
        base += (w < wv) ? wtot[w] : 0;
        Sall += wtot[w];
    }
    int S = min(Sall, MAXS);
    int excl = base + pre - myCnt;
    #pragma unroll
    for (int t = 0; t < 8; t++) {
        if (hv[t] == u) {
            if (excl < MAXS) list[excl] = tid*8 + t;
            excl++;
        }
    }
    __syncthreads();

    int qq = (lane >> 4) & 3;
    int kk = (lane >> 2) & 3;
    int c4 = lane & 3;
    int l15 = lane & 15;
    int i0 = qq, i1 = (qq+1)&3, i2 = (qq+2)&3, i3 = (qq+3)&3;
    const float4* Q4 = (const float4*)&q[(size_t)b*Ln*CQ];
    const float4* K4 = (const float4*)&k[(size_t)b*Ln*CQ];
    const float4* V4 = (const float4*)&v[(size_t)b*Ln*Cn];

    if (S <= SFULL) {
        stage_kv(tid, S, 0, list, K4, V4, ks4, vs4);
        __syncthreads();
        // no barriers below: per-wave divergence in trip counts is safe
        if (wv*16 < S)
            run_sweep<4,MODE>(wv*16, S, 1, list, Q4, ks4, vs4, acc,
                              b, h, qq, lane, c4, l15, kk, i0, i1, i2, i3);
        for (int qb = 128 + wv*4; qb < S; qb += 32)
            run_sweep<1,MODE>(qb, S, 1, list, Q4, ks4, vs4, acc,
                              b, h, qq, lane, c4, l15, kk, i0, i1, i2, i3);
    } else {
        // rare (>5.8 sigma) chunked fallback; uniform barrier counts
        for (int q0s = 0; q0s < S; q0s += 128) {
            int q0 = q0s + wv*16;
            int act = q0 < S;
            Sweep<4> st;
            sweep_init<4>(st, q0, S, act, list, Q4, qq, c4);
            for (int k0 = 0; k0 < S; k0 += SFULL) {
                int nk = min(SFULL, S - k0);
                __syncthreads();
                stage_kv(tid, nk, k0, list, K4, V4, ks4, vs4);
                __syncthreads();
                if (act) sweep_keys<4>(st, nk, ks4, vs4, l15, kk, i0, i1, i2, i3);
            }
            if (act) sweep_fin<4,MODE>(st, acc, b, h, qq, lane, c4);
        }
    }
}

// 256 blocks x 512 threads: outconv + stats + norm fused via grid barrier.
// All 256 blocks co-resident (1 needed/CU, capacity 4/CU by LDS/threads/VGPR).
// y lives only in registers/LDS — never touches HBM. Partial channel sums are
// plain stores (no atomics); final reduce done redundantly per block (~128KB L2).
template<int MODE>
__global__ __launch_bounds__(512, 1) void fused_out_kernel(
        const float* __restrict__ acc, const float* __restrict__ Wo,
        const float* __restrict__ bo, const float* __restrict__ gamma,
        const float* __restrict__ x,
        const float* __restrict__ bnw, const float* __restrict__ bnb,
        float* __restrict__ out,
        float* __restrict__ Psum, float* __restrict__ Psq,
        int* __restrict__ cnt) {
    __shared__ float sWt[Cn*OSTR];   // [c][o] stride 68, 17.4 KB
    __shared__ float sA[Cn*OSTR];    // [c][p] then [o][p], 17.4 KB
    __shared__ float sb[Cn];
    __shared__ float sred[512], sred2[512];
    __shared__ float swv[Cn], sbb[Cn];
    int tid = threadIdx.x;
    int pg = blockIdx.x;             // 64 positions per block
    // coalesced Wo load (lanes <- consecutive c), transpose into LDS
    for (int idx = tid; idx < Cn*Cn; idx += 512) {
        int c = idx & 63, o = idx >> 6;
        sWt[c*OSTR + o] = Wo[o*Cn + c];
    }
    if (tid < Cn) sb[tid] = bo[tid];
    // stage summed acc: 64 pos x 64 ch = 1024 f4
    const float4* a4 = (const float4*)&acc[(size_t)pg*FPOS*Cn];
    #pragma unroll
    for (int r = 0; r < 2; r++) {
        int idx = r*512 + tid;       // p = idx>>4, c4 = idx&15
        int p = idx >> 4, c0 = (idx & 15) * 4;
        float4 t = a4[idx];
        if (MODE == 1) {
            float4 t1 = a4[(size_t)ACCSZ/4   + idx];
            float4 t2 = a4[(size_t)ACCSZ/4*2 + idx];
            float4 t3 = a4[(size_t)ACCSZ/4*3 + idx];
            t.x += t1.x + t2.x + t3.x; t.y += t1.y + t2.y + t3.y;
            t.z += t1.z + t2.z + t3.z; t.w += t1.w + t2.w + t3.w;
        }
        sA[(c0+0)*OSTR + p] = t.x*0.25f;
        sA[(c0+1)*OSTR + p] = t.y*0.25f;
        sA[(c0+2)*OSTR + p] = t.z*0.25f;
        sA[(c0+3)*OSTR + p] = t.w*0.25f;
    }
    __syncthreads();
    float g = gamma[0];
    int p = tid & 63, og = tid >> 6;    // 8 groups x 8 channels
    int gp = pg * FPOS + p;
    int b = gp >> 12, l = gp & (Ln - 1);
    int o0 = og * 8;
    float val[8];
    #pragma unroll
    for (int i = 0; i < 8; i++) val[i] = sb[o0 + i];
    #pragma unroll
    for (int c = 0; c < Cn; c++) {
        float av = sA[c*OSTR + p];          // lanes consecutive p: conflict-free
        const float4 wa = *(const float4*)&sWt[c*OSTR + o0];   // b128 broadcast
        const float4 wb = *(const float4*)&sWt[c*OSTR + o0 + 4];
        val[0] = fmaf(wa.x, av, val[0]); val[1] = fmaf(wa.y, av, val[1]);
        val[2] = fmaf(wa.z, av, val[2]); val[3] = fmaf(wa.w, av, val[3]);
        val[4] = fmaf(wb.x, av, val[4]); val[5] = fmaf(wb.y, av, val[5]);
        val[6] = fmaf(wb.z, av, val[6]); val[7] = fmaf(wb.w, av, val[7]);
    }
    float yv8[8];
    #pragma unroll
    for (int i = 0; i < 8; i++)
        yv8[i] = fmaf(g, val[i], x[((size_t)b*Cn + o0 + i)*Ln + l]);
    // per-block channel partials via LDS transpose (no atomics)
    __syncthreads();                     // sA reads done
    #pragma unroll
    for (int i = 0; i < 8; i++) sA[(o0+i)*OSTR + p] = yv8[i];
    __syncthreads();
    if (tid < Cn) {
        float s = 0.f, s2 = 0.f;
        for (int pp = 0; pp < FPOS; pp++) {
            float yv = sA[tid*OSTR + pp];
            s += yv;
            s2 = fmaf(yv, yv, s2);
        }
        Psum[tid*NBLK_F + pg] = s;
        Psq [tid*NBLK_F + pg] = s2;
    }
    // ---- grid barrier (all 256 blocks co-resident by construction) ----
    __threadfence();
    __syncthreads();
    if (tid == 0) {
        __hip_atomic_fetch_add(cnt, 1, __ATOMIC_ACQ_REL, __HIP_MEMORY_SCOPE_AGENT);
        while (__hip_atomic_load(cnt, __ATOMIC_ACQUIRE, __HIP_MEMORY_SCOPE_AGENT) < NBLK_F)
            __builtin_amdgcn_s_sleep(8);
    }
    __syncthreads();
    // ---- final stats, redundant per block: thread (c=tid>>3, j=tid&7) ----
    {
        int c = tid >> 3, j = tid & 7;
        const float* ps = &Psum[c*NBLK_F + j*32];
        const float* pq = &Psq [c*NBLK_F + j*32];
        float s = 0.f, s2 = 0.f;
        #pragma unroll 8
        for (int i = 0; i < 32; i++) { s += ps[i]; s2 += pq[i]; }
        sred[tid] = s; sred2[tid] = s2;
    }
    __syncthreads();
    if (tid < Cn) {
        float s = 0.f, s2 = 0.f;
        #pragma unroll
        for (int j = 0; j < 8; j++) { s += sred[tid*8 + j]; s2 += sred2[tid*8 + j]; }
        const float n = (float)(Bn*Ln);
        float mu = s / n;
        float var = s2 / n - mu*mu;
        float is = rsqrtf(var + EPSV);
        float w = is * bnw[tid];
        swv[tid] = w;
        sbb[tid] = bnb[tid] - mu * w;
    }
    __syncthreads();
    #pragma unroll
    for (int i = 0; i < 8; i++) {
        int o = o0 + i;
        out[((size_t)b*Cn + o)*Ln + l] = fmaf(yv8[i], swv[o], sbb[o]);
    }
}

extern "C" void kernel_launch(void* const* d_in, const int* in_sizes, int n_in,
                              void* d_out, int out_size, void* d_ws, size_t ws_size,
                              hipStream_t stream) {
    const float* x    = (const float*)d_in[0];
    const int*   hidx = (const int*)  d_in[1];
    const float* Wq   = (const float*)d_in[2];
    const float* bq   = (const float*)d_in[3];
    const float* Wk   = (const float*)d_in[4];
    const float* bk   = (const float*)d_in[5];
    const float* Wv   = (const float*)d_in[6];
    const float* bv   = (const float*)d_in[7];
    const float* Wo   = (const float*)d_in[8];
    const float* bo   = (const float*)d_in[9];
    const float* gam  = (const float*)d_in[10];
    const float* bnw  = (const float*)d_in[11];
    const float* bnb  = (const float*)d_in[12];
    float* out = (float*)d_out;

    float* ws  = (float*)d_ws;
    float* q   = ws;
    float* k   = ws + OFF_K;
    float* v   = ws + OFF_V;
    float* acc = ws + OFF_ACC;

    const size_t bigNeed = ((size_t)OFF_ACC + 4*(size_t)ACCSZ
                            + 2*(size_t)Cn*NBLK_F + 16) * sizeof(float);
    bool big = ws_size >= bigNeed;
    size_t accN = big ? 4*(size_t)ACCSZ : (size_t)ACCSZ;
    float* Psum = acc + accN;
    float* Psq  = Psum + (size_t)Cn*NBLK_F;
    int*   cnt  = (int*)(Psq + (size_t)Cn*NBLK_F);

    proj_kernel<<<Bn*Ln/64*3, 256, 0, stream>>>(x, Wq, bq, Wk, bk, Wv, bv, q, k, v, cnt);
    if (big) {
        attn_kernel<1><<<NBH*NB, 512, 0, stream>>>(q, k, v, hidx, acc);
        fused_out_kernel<1><<<NBLK_F, 512, 0, stream>>>(acc, Wo, bo, gam, x,
                                                        bnw, bnb, out, Psum, Psq, cnt);
    } else {
        hipMemsetAsync(acc, 0, (size_t)ACCSZ*sizeof(float), stream);
        attn_kernel<0><<<NBH*NB, 512, 0, stream>>>(q, k, v, hidx, acc);
        fused_out_kernel<0><<<NBLK_F, 512, 0, stream>>>(acc, Wo, bo, gam, x,
                                                        bnw, bnb, out, Psum, Psq, cnt);
    }
}

// Round 10
// 150.085 us; speedup vs baseline: 1.3520x; 1.3520x over previous
//
#include <hip/hip_runtime.h>
#include <math.h>

#define Bn 4
#define Cn 64
#define Ln 4096
#define CQ 16
#define NH 4
#define NB 32
#define EPSV 1e-5f

#define MAXS 384    // max bucket size (mean 128, sigma ~11)
#define SFULL 192   // full-bucket LDS staging limit (mean+5.8sigma)

#define QSZ   (Bn*Ln*CQ)      // 262144 floats
#define VSZ   (Bn*Ln*Cn)      // 1048576 floats
#define ACCSZ (Bn*Ln*Cn)
#define NBH   (Bn*NH)         // 16

// layout (float units): [q][k][v][acc x4|x1][ssumP(256)][ssqP(256)]
#define OFF_K   QSZ
#define OFF_V   (2*QSZ)
#define OFF_ACC (2*QSZ + VSZ)

#define LOG2E 1.44269504088896f
#define WSTR 36     // proj sWt stride: 36c+4og stays 16B-aligned, banks spread
#define OSTR 68     // outconv sWt stride: 68c+4o0 16B-aligned

// 768 blocks x 512 threads: (pos-group of 64) x (row-third of 32); og (tid>>6,
// 8 groups) owns 4 rows -> 24 waves/CU (6/SIMD), 2x R7's latency hiding.
__global__ __launch_bounds__(512) void proj_kernel(
        const float* __restrict__ x,
        const float* __restrict__ Wq, const float* __restrict__ bq,
        const float* __restrict__ Wk, const float* __restrict__ bk,
        const float* __restrict__ Wv, const float* __restrict__ bv,
        float* __restrict__ q, float* __restrict__ k, float* __restrict__ v) {
    __shared__ float sWt[Cn*WSTR];   // [c][rr] stride 36
    __shared__ float sb[32];
    int tid = threadIdx.x;
    int third = blockIdx.x % 3;
    int pg    = blockIdx.x / 3;
    int rbase = third * 32;
    // coalesced weight load: consecutive lanes <- consecutive c of one W row
    for (int idx = tid; idx < 32*Cn; idx += 512) {
        int c = idx & 63, rr = idx >> 6;
        int r = rbase + rr;
        float w;
        if (r < 16)      w = Wq[r*Cn + c];
        else if (r < 32) w = Wk[(r-16)*Cn + c];
        else             w = Wv[(r-32)*Cn + c];
        sWt[c*WSTR + rr] = w;
    }
    if (tid < 32) {
        int r = rbase + tid;
        sb[tid] = (r < 16) ? bq[r] : (r < 32 ? bk[r-16] : bv[r-32]);
    }
    __syncthreads();
    int p = tid & 63, og = tid >> 6;       // og uniform per wave, 0..7
    int gp = pg * 64 + p;                  // flattened position b*L + l
    int b = gp >> 12, l = gp & (Ln - 1);
    const float* xp = &x[b*Cn*Ln + l];
    int rr0 = og * 4;                      // 4 rows per group
    float val[4];
    #pragma unroll
    for (int i = 0; i < 4; i++) val[i] = sb[rr0 + i];
    #pragma unroll
    for (int c0 = 0; c0 < Cn; c0 += 8) {
        float xv[8];
        #pragma unroll
        for (int i = 0; i < 8; i++) xv[i] = xp[(c0 + i)*Ln];   // coalesced; L1-hot
        #pragma unroll
        for (int i = 0; i < 8; i++) {
            const float4 wa = *(const float4*)&sWt[(c0 + i)*WSTR + rr0];
            float xvi = xv[i];
            val[0] = fmaf(wa.x, xvi, val[0]); val[1] = fmaf(wa.y, xvi, val[1]);
            val[2] = fmaf(wa.z, xvi, val[2]); val[3] = fmaf(wa.w, xvi, val[3]);
        }
    }
    float4 t0 = make_float4(val[0], val[1], val[2], val[3]);
    float4* q4 = (float4*)&q[gp*CQ];
    float4* k4 = (float4*)&k[gp*CQ];
    float4* v4 = (float4*)&v[gp*Cn];
    // wave-uniform write map: third0 -> q/k, third1 -> v[0..7], third2 -> v[8..15]
    if (third == 0)      { if (og < 4) q4[og] = t0; else k4[og-4] = t0; }
    else if (third == 1) { v4[og]   = t0; }
    else                 { v4[og+8] = t0; }
}

// quad (4-lane) butterfly sum via DPP quad_perm — VALU pipe, no LDS
__device__ __forceinline__ float quad_reduce_sum(float d) {
    d += __int_as_float(__builtin_amdgcn_mov_dpp(__float_as_int(d), 0xB1, 0xF, 0xF, true));
    d += __int_as_float(__builtin_amdgcn_mov_dpp(__float_as_int(d), 0x4E, 0xF, 0xF, true));
    return d;
}

// sum over the 4 lanes {r, r-4, r-8, r-12} within a row of 16 (same c4 class);
// result valid at row-tail lanes 12..15. row_shr:4 = 0x114, row_shr:8 = 0x118.
__device__ __forceinline__ float rowsum16(float x) {
    x += __int_as_float(__builtin_amdgcn_mov_dpp(__float_as_int(x), 0x114, 0xF, 0xF, true));
    x += __int_as_float(__builtin_amdgcn_mov_dpp(__float_as_int(x), 0x118, 0xF, 0xF, true));
    return x;
}

// wave covers 4*NS queries per sweep: lane = (qq=l>>4, kk=(l>>2)&3, c4=l&3),
// slot s covers queries q0+s*4 .. +3 via the 4 qq-groups.
// o[s][t] = chs ((qq+t)&3)*16 + c4*4 .. +3.  ir[s]<0 marks inactive slot.
template<int NS> struct Sweep {
    float4 qr[NS];     // lane's c4-quarter of each query, prescaled by log2e
    float4 o[NS][4];
    float  lsum[NS];
    int    ir[NS];
};

template<int NS>
__device__ __forceinline__ void sweep_init(Sweep<NS>& st, int q0, int S, int act,
        const int* list, const float4* Q4, int qq, int c4) {
    #pragma unroll
    for (int s = 0; s < NS; s++) {
        int qi = q0 + s*4 + qq;
        int a = act && (qi < S);
        st.ir[s] = a ? list[qi] : -1;
        float4 t = make_float4(0.f, 0.f, 0.f, 0.f);
        if (a) {
            t = Q4[(size_t)st.ir[s]*4 + c4];
            t.x *= LOG2E; t.y *= LOG2E; t.z *= LOG2E; t.w *= LOG2E;
        }
        st.qr[s] = t;
        st.lsum[s] = 0.f;
        #pragma unroll
        for (int tt = 0; tt < 4; tt++) st.o[s][tt] = make_float4(0.f, 0.f, 0.f, 0.f);
    }
}

// one 4-key block: 1 K b128 + 4 V b128, all conflict-free (R5-proven form)
template<int NS, bool MASKED>
__device__ __forceinline__ void kb_step(Sweep<NS>& st, int kb, int nkv,
        const float4* ks4, const float4* vs4, int l15, int kk,
        int i0, int i1, int i2, int i3) {
    const float4 kq = ks4[kb*16 + l15];
    const float4 va = vs4[kb*64 + i0*16 + l15];
    const float4 vb = vs4[kb*64 + i1*16 + l15];
    const float4 vc = vs4[kb*64 + i2*16 + l15];
    const float4 vd = vs4[kb*64 + i3*16 + l15];
    #pragma unroll
    for (int s = 0; s < NS; s++) {
        float d = st.qr[s].x * kq.x;
        d = fmaf(st.qr[s].y, kq.y, d);
        d = fmaf(st.qr[s].z, kq.z, d);
        d = fmaf(st.qr[s].w, kq.w, d);
        d = quad_reduce_sum(d);                 // full 16-ch dot in all 4 quad lanes
        float pw = __builtin_amdgcn_exp2f(d);
        if (MASKED) pw = ((kb*4 + kk) < nkv) ? pw : 0.f;
        st.lsum[s] += pw;
        st.o[s][0].x = fmaf(pw, va.x, st.o[s][0].x); st.o[s][0].y = fmaf(pw, va.y, st.o[s][0].y);
        st.o[s][0].z = fmaf(pw, va.z, st.o[s][0].z); st.o[s][0].w = fmaf(pw, va.w, st.o[s][0].w);
        st.o[s][1].x = fmaf(pw, vb.x, st.o[s][1].x); st.o[s][1].y = fmaf(pw, vb.y, st.o[s][1].y);
        st.o[s][1].z = fmaf(pw, vb.z, st.o[s][1].z); st.o[s][1].w = fmaf(pw, vb.w, st.o[s][1].w);
        st.o[s][2].x = fmaf(pw, vc.x, st.o[s][2].x); st.o[s][2].y = fmaf(pw, vc.y, st.o[s][2].y);
        st.o[s][2].z = fmaf(pw, vc.z, st.o[s][2].z); st.o[s][2].w = fmaf(pw, vc.w, st.o[s][2].w);
        st.o[s][3].x = fmaf(pw, vd.x, st.o[s][3].x); st.o[s][3].y = fmaf(pw, vd.y, st.o[s][3].y);
        st.o[s][3].z = fmaf(pw, vd.z, st.o[s][3].z); st.o[s][3].w = fmaf(pw, vd.w, st.o[s][3].w);
    }
}

template<int NS>
__device__ __forceinline__ void sweep_keys(Sweep<NS>& st, int nk,
        const float4* ks4, const float4* vs4, int l15, int kk,
        int i0, int i1, int i2, int i3) {
    int nf = nk >> 2;
    for (int kb = 0; kb < nf; kb++)
        kb_step<NS,false>(st, kb, nk, ks4, vs4, l15, kk, i0, i1, i2, i3);
    if (nk & 3)
        kb_step<NS,true>(st, nf, nk, ks4, vs4, l15, kk, i0, i1, i2, i3);
}

// reduce o/lsum over kk (2 DPP row-tail adds, pure VALU); tail lanes 12..15
// of each row (c4 = 0..3) hold the query's full 64 channels; normalize+store
template<int NS, int MODE>
__device__ __forceinline__ void sweep_fin(Sweep<NS>& st, float* __restrict__ acc,
        int b, int h, int qq, int lane, int c4) {
    #pragma unroll
    for (int s = 0; s < NS; s++) {
        st.lsum[s] = rowsum16(st.lsum[s]);
        #pragma unroll
        for (int t = 0; t < 4; t++) {
            st.o[s][t].x = rowsum16(st.o[s][t].x);
            st.o[s][t].y = rowsum16(st.o[s][t].y);
            st.o[s][t].z = rowsum16(st.o[s][t].z);
            st.o[s][t].w = rowsum16(st.o[s][t].w);
        }
    }
    if ((lane & 15) < 12) return;
    #pragma unroll
    for (int s = 0; s < NS; s++) {
        if (st.ir[s] >= 0) {
            float inv = 1.f / st.lsum[s];
            #pragma unroll
            for (int t = 0; t < 4; t++) {
                float4 r;
                r.x = st.o[s][t].x * inv; r.y = st.o[s][t].y * inv;
                r.z = st.o[s][t].z * inv; r.w = st.o[s][t].w * inv;
                int ch = ((qq + t) & 3)*16 + c4*4;
                if (MODE == 1) {
                    *(float4*)&acc[(((size_t)h*Bn + b)*Ln + st.ir[s])*Cn + ch] = r;
                } else {
                    float* ap = &acc[((size_t)b*Ln + st.ir[s])*Cn + ch];
                    atomicAdd(&ap[0], r.x); atomicAdd(&ap[1], r.y);
                    atomicAdd(&ap[2], r.z); atomicAdd(&ap[3], r.w);
                }
            }
        }
    }
}

template<int NS, int MODE>
__device__ __forceinline__ void run_sweep(int q0, int S, int act,
        const int* list, const float4* Q4,
        const float4* ks4, const float4* vs4, float* __restrict__ acc,
        int b, int h, int qq, int lane, int c4, int l15, int kk,
        int i0, int i1, int i2, int i3) {
    Sweep<NS> st;
    sweep_init<NS>(st, q0, S, act, list, Q4, qq, c4);
    sweep_keys<NS>(st, S, ks4, vs4, l15, kk, i0, i1, i2, i3);
    sweep_fin<NS,MODE>(st, acc, b, h, qq, lane, c4);
}

// tiled staging (NT=512): ks4[j*4+c] = K[list[j]] quarter c;
// vs4[(j>>2)*64 + i*16 + (j&3)*4 + c] = V[list[j]][i*16 + c*4 ..+3]
__device__ __forceinline__ void stage_kv(int tid, int nk, int k0, const int* list,
        const float4* K4, const float4* V4, float4* ks4, float4* vs4) {
    const float4 z = make_float4(0.f, 0.f, 0.f, 0.f);
    int nb4 = (nk + 3) >> 2;
    for (int G = tid; G < nb4*16; G += 512) {
        int j = G >> 2;
        ks4[G] = (j < nk) ? K4[(size_t)list[k0 + j]*4 + (G & 3)] : z;
    }
    for (int F = tid; F < nb4*64; F += 512) {
        int kb = F >> 6, ii = (F >> 4) & 3, k2 = (F >> 2) & 3, cc = F & 3;
        int j = kb*4 + k2;
        vs4[F] = (j < nk) ? V4[(size_t)list[k0 + j]*16 + ii*4 + cc] : z;
    }
}

// 512 blocks x 512 threads (8 waves), 2 blocks/CU resident (62KB LDS).
template<int MODE>
__global__ __launch_bounds__(512, 2) void attn_kernel(
        const float* __restrict__ q, const float* __restrict__ k,
        const float* __restrict__ v, const int* __restrict__ hidx,
        float* __restrict__ acc) {
    __shared__ int list[MAXS];
    __shared__ int wtot[8];
    __shared__ float4 ks4[SFULL*4];    // 12 KB
    __shared__ float4 vs4[SFULL*16];   // 48 KB
    int blk = blockIdx.x;              // = bh*NB + u
    int u  = blk & (NB-1);
    int bh = blk >> 5;
    int b  = bh >> 2;
    int h  = bh & 3;
    int tid = threadIdx.x;

    // ---- deterministic ascending bucket list via wave scan (8 ints/thread) ----
    const int4* hp4 = (const int4*)&hidx[bh*Ln + tid*8];
    int hv[8];
    #pragma unroll
    for (int t = 0; t < 2; t++) {
        int4 tmp = hp4[t];
        hv[t*4+0]=tmp.x; hv[t*4+1]=tmp.y; hv[t*4+2]=tmp.z; hv[t*4+3]=tmp.w;
    }
    int myCnt = 0;
    #pragma unroll
    for (int t = 0; t < 8; t++) myCnt += (hv[t] == u);
    int lane = tid & 63, wv = tid >> 6;
    int pre = myCnt;
    #pragma unroll
    for (int d = 1; d < 64; d <<= 1) {
        int t = __shfl_up(pre, d, 64);
        if (lane >= d) pre += t;
    }
    if (lane == 63) wtot[wv] = pre;
    __syncthreads();
    int base = 0, Sall = 0;
    #pragma unroll
    for (int w = 0; w < 8; w++) {
        base += (w < wv) ? wtot[w] : 0;
        Sall += wtot[w];
    }
    int S = min(Sall, MAXS);
    int excl = base + pre - myCnt;
    #pragma unroll
    for (int t = 0; t < 8; t++) {
        if (hv[t] == u) {
            if (excl < MAXS) list[excl] = tid*8 + t;
            excl++;
        }
    }
    __syncthreads();

    int qq = (lane >> 4) & 3;
    int kk = (lane >> 2) & 3;
    int c4 = lane & 3;
    int l15 = lane & 15;
    int i0 = qq, i1 = (qq+1)&3, i2 = (qq+2)&3, i3 = (qq+3)&3;
    const float4* Q4 = (const float4*)&q[(size_t)b*Ln*CQ];
    const float4* K4 = (const float4*)&k[(size_t)b*Ln*CQ];
    const float4* V4 = (const float4*)&v[(size_t)b*Ln*Cn];

    if (S <= SFULL) {
        stage_kv(tid, S, 0, list, K4, V4, ks4, vs4);
        __syncthreads();
        // no barriers below: per-wave divergence in trip counts is safe
        if (wv*16 < S)
            run_sweep<4,MODE>(wv*16, S, 1, list, Q4, ks4, vs4, acc,
                              b, h, qq, lane, c4, l15, kk, i0, i1, i2, i3);
        for (int qb = 128 + wv*4; qb < S; qb += 32)
            run_sweep<1,MODE>(qb, S, 1, list, Q4, ks4, vs4, acc,
                              b, h, qq, lane, c4, l15, kk, i0, i1, i2, i3);
    } else {
        // rare (>5.8 sigma) chunked fallback; uniform barrier counts
        for (int q0s = 0; q0s < S; q0s += 128) {
            int q0 = q0s + wv*16;
            int act = q0 < S;
            Sweep<4> st;
            sweep_init<4>(st, q0, S, act, list, Q4, qq, c4);
            for (int k0 = 0; k0 < S; k0 += SFULL) {
                int nk = min(SFULL, S - k0);
                __syncthreads();
                stage_kv(tid, nk, k0, list, K4, V4, ks4, vs4);
                __syncthreads();
                if (act) sweep_keys<4>(st, nk, ks4, vs4, l15, kk, i0, i1, i2, i3);
            }
            if (act) sweep_fin<4,MODE>(st, acc, b, h, qq, lane, c4);
        }
    }
}

// 512 blocks x 512 threads x 32 positions: 16 ch-groups of 4 -> 16 waves/CU
// (4/SIMD, 2x R7). acc staged in one round; stride-33 sA / stride-68 sWt.
template<int MODE>
__global__ __launch_bounds__(512) void outconv_kernel(
        const float* __restrict__ acc, const float* __restrict__ Wo,
        const float* __restrict__ bo, const float* __restrict__ gamma,
        const float* __restrict__ x, float* __restrict__ y) {
    __shared__ float sWt[Cn*OSTR];   // [c][o] stride 68, 17.4 KB
    __shared__ float sA[Cn*33];      // [c][p] stride 33, conflict-free
    __shared__ float sb[Cn];
    int tid = threadIdx.x;
    int pg = blockIdx.x;             // 32 positions per block
    // coalesced Wo load: consecutive lanes <- consecutive c of one Wo row
    for (int idx = tid; idx < Cn*Cn; idx += 512) {
        int c = idx & 63, o = idx >> 6;
        sWt[c*OSTR + o] = Wo[o*Cn + c];
    }
    if (tid < Cn) sb[tid] = bo[tid];
    // stage summed acc: 32 pos x 64 ch = 512 f4, one per thread
    const float4* a4 = (const float4*)&acc[(size_t)pg*32*Cn];
    {
        int idx = tid;               // p = idx>>4, c4 = idx&15
        int p = idx >> 4, c0 = (idx & 15) * 4;
        float4 t = a4[idx];
        if (MODE == 1) {
            float4 t1 = a4[(size_t)ACCSZ/4   + idx];
            float4 t2 = a4[(size_t)ACCSZ/4*2 + idx];
            float4 t3 = a4[(size_t)ACCSZ/4*3 + idx];
            t.x += t1.x + t2.x + t3.x; t.y += t1.y + t2.y + t3.y;
            t.z += t1.z + t2.z + t3.z; t.w += t1.w + t2.w + t3.w;
        }
        sA[(c0+0)*33 + p] = t.x*0.25f;   // banks 2 lanes/bank: free
        sA[(c0+1)*33 + p] = t.y*0.25f;
        sA[(c0+2)*33 + p] = t.z*0.25f;
        sA[(c0+3)*33 + p] = t.w*0.25f;
    }
    __syncthreads();
    float g = gamma[0];
    int p = tid & 31, og = tid >> 5;    // 16 groups x 4 channels
    int gp = pg * 32 + p;
    int b = gp >> 12, l = gp & (Ln - 1);
    int o0 = og * 4;
    float val[4];
    #pragma unroll
    for (int i = 0; i < 4; i++) val[i] = sb[o0 + i];
    #pragma unroll
    for (int c = 0; c < Cn; c++) {
        float av = sA[c*33 + p];        // p-major: conflict-free
        const float4 wa = *(const float4*)&sWt[c*OSTR + o0];   // b128, 2-way bcast
        val[0] = fmaf(wa.x, av, val[0]); val[1] = fmaf(wa.y, av, val[1]);
        val[2] = fmaf(wa.z, av, val[2]); val[3] = fmaf(wa.w, av, val[3]);
    }
    #pragma unroll
    for (int i = 0; i < 4; i++) {
        int o = o0 + i;
        float yv = fmaf(g, val[i], x[(b*Cn + o)*Ln + l]);
        y[(b*Cn + o)*Ln + l] = yv;
    }
}

// 256 blocks = (c, part); plain-store partials (no memset, no atomics)
__global__ __launch_bounds__(256) void stats_kernel(
        const float* __restrict__ y, float* __restrict__ ssumP, float* __restrict__ ssqP) {
    int c = blockIdx.x >> 2;       // channel
    int part = blockIdx.x & 3;     // batch index
    int tid = threadIdx.x;
    const float4* yp = (const float4*)&y[(part*Cn + c)*Ln];
    float s = 0.f, s2 = 0.f;
    #pragma unroll
    for (int i = 0; i < 4; i++) {
        float4 t = yp[i*256 + tid];
        s  += t.x + t.y + t.z + t.w;
        s2 += t.x*t.x + t.y*t.y + t.z*t.z + t.w*t.w;
    }
    #pragma unroll
    for (int w = 1; w < 64; w <<= 1) {
        s  += __shfl_xor(s,  w, 64);
        s2 += __shfl_xor(s2, w, 64);
    }
    __shared__ float rs[4], rs2[4];
    int wv = tid >> 6;
    if ((tid & 63) == 0) { rs[wv] = s; rs2[wv] = s2; }
    __syncthreads();
    if (tid == 0) {
        ssumP[blockIdx.x] = rs[0]+rs[1]+rs[2]+rs[3];
        ssqP[blockIdx.x]  = rs2[0]+rs2[1]+rs2[2]+rs2[3];
    }
}

__global__ __launch_bounds__(256) void norm_kernel(
        const float* __restrict__ y,
        const float* __restrict__ ssumP, const float* __restrict__ ssqP,
        const float* __restrict__ bnw, const float* __restrict__ bnb,
        float* __restrict__ out) {
    int idx = blockIdx.x * 256 + threadIdx.x;  // float4 index
    int flat = idx * 4;
    int c = (flat >> 12) & 63;
    float s = 0.f, s2 = 0.f;
    #pragma unroll
    for (int hh = 0; hh < 4; hh++) { s += ssumP[c*4+hh]; s2 += ssqP[c*4+hh]; }
    const float n = (float)(Bn*Ln);
    float mu = s / n;
    float var = s2 / n - mu*mu;
    float is = rsqrtf(var + EPSV);
    float w = is * bnw[c];
    float bb = bnb[c] - mu * w;
    float4 t = ((const float4*)y)[idx];
    float4 r;
    r.x = t.x*w + bb; r.y = t.y*w + bb; r.z = t.z*w + bb; r.w = t.w*w + bb;
    ((float4*)out)[idx] = r;
}

extern "C" void kernel_launch(void* const* d_in, const int* in_sizes, int n_in,
                              void* d_out, int out_size, void* d_ws, size_t ws_size,
                              hipStream_t stream) {
    const float* x    = (const float*)d_in[0];
    const int*   hidx = (const int*)  d_in[1];
    const float* Wq   = (const float*)d_in[2];
    const float* bq   = (const float*)d_in[3];
    const float* Wk   = (const float*)d_in[4];
    const float* bk   = (const float*)d_in[5];
    const float* Wv   = (const float*)d_in[6];
    const float* bv   = (const float*)d_in[7];
    const float* Wo   = (const float*)d_in[8];
    const float* bo   = (const float*)d_in[9];
    const float* gam  = (const float*)d_in[10];
    const float* bnw  = (const float*)d_in[11];
    const float* bnb  = (const float*)d_in[12];
    float* out = (float*)d_out;

    float* ws  = (float*)d_ws;
    float* q   = ws;
    float* k   = ws + OFF_K;
    float* v   = ws + OFF_V;
    float* acc = ws + OFF_ACC;
    float* y   = ws;            // overlays q/k/v after attn

    const size_t bigNeed = ((size_t)OFF_ACC + 4*(size_t)ACCSZ + 512) * sizeof(float);
    bool big = ws_size >= bigNeed;
    float* ssumP = acc + (big ? 4*(size_t)ACCSZ : (size_t)ACCSZ);
    float* ssqP  = ssumP + 256;

    proj_kernel<<<Bn*Ln/64*3, 512, 0, stream>>>(x, Wq, bq, Wk, bk, Wv, bv, q, k, v);
    if (big) {
        attn_kernel<1><<<NBH*NB, 512, 0, stream>>>(q, k, v, hidx, acc);
        outconv_kernel<1><<<Bn*Ln/32, 512, 0, stream>>>(acc, Wo, bo, gam, x, y);
    } else {
        hipMemsetAsync(acc, 0, (size_t)ACCSZ*sizeof(float), stream);
        attn_kernel<0><<<NBH*NB, 512, 0, stream>>>(q, k, v, hidx, acc);
        outconv_kernel<0><<<Bn*Ln/32, 512, 0, stream>>>(acc, Wo, bo, gam, x, y);
    }
    stats_kernel<<<Cn*4, 256, 0, stream>>>(y, ssumP, ssqP);
    norm_kernel<<<Bn*Cn*Ln/4/256, 256, 0, stream>>>(y, ssumP, ssqP, bnw, bnb, out);
}